// Round 3
// baseline (264.421 us; speedup 1.0000x reference)
//
#include <hip/hip_runtime.h>
#include <hip/hip_bf16.h>
#include <cstdint>
#include <cstddef>

#define T_TOK 8192
#define MDIM  4096
#define NEXP  64
#define CAP   128
#define KSPL  4                                   // split-K for the MFMA GEMM
#define TEC   ((size_t)T_TOK * NEXP * CAP)        // 67,108,864
#define OUTN  ((size_t)(1 + 2 * TEC))             // 134,217,729 floats

typedef __attribute__((ext_vector_type(8))) short bf16x8;   // 8 bf16 (4 VGPR)
typedef __attribute__((ext_vector_type(4))) float f32x4;    // MFMA acc

// ---------------------------------------------------------------------------
// Split Wg (f32) into hi/lo bf16 planes: wg ~= wh + wl, |err| ~ 2^-18.
// ---------------------------------------------------------------------------
__global__ __launch_bounds__(256) void wsplit(
    const float* __restrict__ wg, short* __restrict__ wh,
    short* __restrict__ wl) {
  const int i = blockIdx.x * 256 + threadIdx.x;       // over float4 units
  const float4 v = ((const float4*)wg)[i];
  short4 h, l;
  const float a[4] = {v.x, v.y, v.z, v.w};
  short* hp = &h.x; short* lp = &l.x;
#pragma unroll
  for (int j = 0; j < 4; ++j) {
    const __hip_bfloat16 hb = __float2bfloat16(a[j]);
    const float r = a[j] - __bfloat162float(hb);
    const __hip_bfloat16 lb = __float2bfloat16(r);
    hp[j] = __builtin_bit_cast(short, hb);
    lp[j] = __builtin_bit_cast(short, lb);
  }
  ((short4*)wh)[i] = h;
  ((short4*)wl)[i] = l;
}

// ---------------------------------------------------------------------------
// Fused: split-bf16 MFMA GEMM (logits partials) + zero-fill of d_out.
// Role by blockIdx.x % 3: {0} -> GEMM, {1,2} -> fill slice.
// GEMM: per wave 16 tokens x 64 experts x K-chunk 1024, no LDS.
//   logits = xh*wh + xh*wl + xl*wh  (3 MFMA passes, f32 accumulate)
// ---------------------------------------------------------------------------
__global__ __launch_bounds__(256) void gemm_fill(
    const float* __restrict__ x, const short* __restrict__ wh,
    const short* __restrict__ wl, float* __restrict__ part,
    float* __restrict__ out, float* __restrict__ esum, int nfill) {
  const int bid = blockIdx.x;
  const int tid = threadIdx.x;

  if (bid % 3) {                 // ---- fill role: pure HBM write ----
    const int fb = (bid / 3) * 2 + (bid % 3) - 1;     // 0..nfill-1
    const float4 z = make_float4(0.f, 0.f, 0.f, 0.f);
    float4* o4 = (float4*)out;
    const int total4 = (int)((OUTN - 1) / 4);         // 33,554,432
    const int stride = nfill * 256;
    for (int i = fb * 256 + tid; i < total4; i += stride) o4[i] = z;
    if (fb == 0) {
      if (tid == 0) out[OUTN - 1] = 0.f;              // tail element
      if (tid < NEXP) esum[tid] = 0.f;
    }
    return;
  }

  // ---- GEMM role ----
  const int gid  = bid / 3;            // 0..511
  const int ksub = gid & (KSPL - 1);   // K quarter
  const int tg   = gid >> 2;           // token group of 64
  const int wid  = tid >> 6;
  const int lane = tid & 63;
  const int t0   = tg * 64 + wid * 16;
  const int row  = lane & 15;          // A: token row / B: expert col
  const int kg   = lane >> 4;          // k-subgroup (x8 elements)

  const float* xp  = x  + (size_t)(t0 + row) * MDIM + ksub * (MDIM / KSPL) + kg * 8;
  const short* whp = wh + (size_t)row * MDIM + ksub * (MDIM / KSPL) + kg * 8;
  const short* wlp = wl + (size_t)row * MDIM + ksub * (MDIM / KSPL) + kg * 8;

  f32x4 acc[4] = {{0.f,0.f,0.f,0.f},{0.f,0.f,0.f,0.f},
                  {0.f,0.f,0.f,0.f},{0.f,0.f,0.f,0.f}};

#pragma unroll 2
  for (int s = 0; s < (MDIM / KSPL) / 32; ++s) {      // 32 K-steps
    const float4 a0 = *(const float4*)xp;
    const float4 a1 = *(const float4*)(xp + 4);
    const float av[8] = {a0.x, a0.y, a0.z, a0.w, a1.x, a1.y, a1.z, a1.w};
    bf16x8 ah, al;
#pragma unroll
    for (int j = 0; j < 8; ++j) {
      const __hip_bfloat16 hb = __float2bfloat16(av[j]);
      const float r = av[j] - __bfloat162float(hb);
      const __hip_bfloat16 lb = __float2bfloat16(r);
      ah[j] = __builtin_bit_cast(short, hb);
      al[j] = __builtin_bit_cast(short, lb);
    }
#pragma unroll
    for (int tile = 0; tile < 4; ++tile) {
      const bf16x8 bh = *(const bf16x8*)(whp + tile * 16 * MDIM);
      const bf16x8 bl = *(const bf16x8*)(wlp + tile * 16 * MDIM);
      acc[tile] = __builtin_amdgcn_mfma_f32_16x16x32_bf16(ah, bh, acc[tile], 0, 0, 0);
      acc[tile] = __builtin_amdgcn_mfma_f32_16x16x32_bf16(ah, bl, acc[tile], 0, 0, 0);
      acc[tile] = __builtin_amdgcn_mfma_f32_16x16x32_bf16(al, bh, acc[tile], 0, 0, 0);
    }
    xp += 32; whp += 32; wlp += 32;
  }

  // C/D layout: col = lane&15 (expert), row = (lane>>4)*4 + reg (token)
#pragma unroll
  for (int tile = 0; tile < 4; ++tile)
#pragma unroll
    for (int r = 0; r < 4; ++r)
      part[((size_t)ksub * T_TOK + t0 + kg * 4 + r) * NEXP + tile * 16 + row] =
          acc[tile][r];
}

// ---------------------------------------------------------------------------
// Reduce split-K, softmax + argmax (tie -> min index). 16 tokens per block.
// ---------------------------------------------------------------------------
__global__ __launch_bounds__(256) void softmax_stats(
    const float* __restrict__ part, int* __restrict__ idx,
    float* __restrict__ gval, float* __restrict__ esum) {
  const int tid  = threadIdx.x;
  const int wid  = tid >> 6;
  const int lane = tid & 63;

  float gl = 0.f;
#pragma unroll
  for (int j = 0; j < 4; ++j) {
    const int t = blockIdx.x * 16 + wid * 4 + j;
    float v = 0.f;
#pragma unroll
    for (int s = 0; s < KSPL; ++s)
      v += part[((size_t)s * T_TOK + t) * NEXP + lane];
    float m = v; int mi = lane;
#pragma unroll
    for (int d = 32; d >= 1; d >>= 1) {
      const float om = __shfl_xor(m, d);
      const int   oi = __shfl_xor(mi, d);
      if (om > m || (om == m && oi < mi)) { m = om; mi = oi; }
    }
    const float e = expf(v - m);
    float denom = e;
#pragma unroll
    for (int d = 32; d >= 1; d >>= 1) denom += __shfl_xor(denom, d);
    gl += e / denom;
    if (lane == 0) { idx[t] = mi; gval[t] = 1.0f / denom; }
  }

  __shared__ float sg[4][64];
  sg[wid][lane] = gl;
  __syncthreads();
  if (tid < 64)
    atomicAdd(&esum[tid], sg[0][tid] + sg[1][tid] + sg[2][tid] + sg[3][tid]);
}

// ---------------------------------------------------------------------------
// Per-expert scan + scatter + l_aux. One wave per expert, idx staged in LDS.
// ---------------------------------------------------------------------------
__global__ __launch_bounds__(256) void scan_scatter(
    const int* __restrict__ idx, const float* __restrict__ gval,
    const float* __restrict__ esum, float* __restrict__ out) {
  __shared__ int sidx[T_TOK];           // 32 KB
  const int tid = threadIdx.x;
  for (int i = tid; i < T_TOK / 4; i += 256)
    ((int4*)sidx)[i] = ((const int4*)idx)[i];
  __syncthreads();

  const int e    = blockIdx.x * 4 + (tid >> 6);
  const int lane = tid & 63;
  int carry = 0;
#pragma unroll 4
  for (int base = 0; base < T_TOK; base += 64) {
    const int t = base + lane;
    const bool flag = (sidx[t] == e);
    const unsigned long long mask = __ballot(flag);
    if (flag) {
      const int p = carry + __popcll(mask & ((1ull << lane) - 1ull));
      if (p < CAP) {
        const size_t off = ((size_t)t * NEXP + e) * CAP + p;
        out[1 + off]       = gval[t];
        out[1 + TEC + off] = 1.0f;
      }
    }
    carry += __popcll(mask);
  }
  if (lane == 0)                        // ce uses pre-drop count = carry
    atomicAdd(out, esum[e] * (float)carry *
                   ((float)NEXP / ((float)T_TOK * (float)T_TOK)));
}

extern "C" void kernel_launch(void* const* d_in, const int* in_sizes, int n_in,
                              void* d_out, int out_size, void* d_ws, size_t ws_size,
                              hipStream_t stream) {
  const float* x  = (const float*)d_in[0];
  const float* wg = (const float*)d_in[1];
  float* out = (float*)d_out;

  // ws layout: wh/wl bf16 planes, then split-K partials, then small arrays
  short* wh   = (short*)d_ws;                               // 64*4096 bf16
  short* wl   = wh + (size_t)NEXP * MDIM;
  float* part = (float*)(wl + (size_t)NEXP * MDIM);         // KSPL*T*E f32
  int*   idx  = (int*)(part + (size_t)KSPL * T_TOK * NEXP);
  float* gval = (float*)(idx + T_TOK);
  float* esum = (float*)(gval + T_TOK);

  const int ngemm = 128 * KSPL;        // 512
  const int nfill = ngemm * 2;         // 1024

  wsplit<<<(NEXP * MDIM / 4) / 256, 256, 0, stream>>>(wg, wh, wl);
  gemm_fill<<<ngemm + nfill, 256, 0, stream>>>(x, wh, wl, part, out, esum, nfill);
  softmax_stats<<<T_TOK / 16, 256, 0, stream>>>(part, idx, gval, esum);
  scan_scatter<<<NEXP / 4, 256, 0, stream>>>(idx, gval, esum, out);
}

// Round 4
// 238.374 us; speedup vs baseline: 1.1093x; 1.1093x over previous
//
#include <hip/hip_runtime.h>
#include <hip/hip_bf16.h>
#include <cstdint>
#include <cstddef>

#define T_TOK 8192
#define MDIM  4096
#define NEXP  64
#define CAP   128
#define TEC   ((size_t)T_TOK * NEXP * CAP)        // 67,108,864
#define OUTN  ((size_t)(1 + 2 * TEC))             // 134,217,729 floats
#define NG    128                                 // GEMM blocks (first in grid)
#define NF    1152                                // fill blocks
#define BK    64
#define NSTEP (MDIM / BK)                         // 64

typedef __attribute__((ext_vector_type(8))) short bf16x8;   // 8 bf16 = 4 VGPR
typedef __attribute__((ext_vector_type(4))) float f32x4;    // MFMA acc

// split f32 -> hi bf16 + lo bf16 (residual), |err| ~ 2^-18 relative
__device__ __forceinline__ void split8(const float* f, bf16x8& h, bf16x8& l) {
#pragma unroll
  for (int j = 0; j < 8; ++j) {
    const __hip_bfloat16 hb = __float2bfloat16(f[j]);
    const float r = f[j] - __bfloat162float(hb);
    h[j] = __builtin_bit_cast(short, hb);
    l[j] = __builtin_bit_cast(short, __float2bfloat16(r));
  }
}

// ---------------------------------------------------------------------------
// Fused: logits GEMM (split-bf16 MFMA, B LDS-staged) + zero-fill of d_out.
// bid < NG: GEMM block (64 tokens x 64 experts x K=4096).
// bid >= NG: fill a contiguous ~466KB chunk of d_out with zeros.
// ---------------------------------------------------------------------------
__global__ __launch_bounds__(256) void gemm_fill(
    const float* __restrict__ x, const float* __restrict__ wg,
    float* __restrict__ logits, float* __restrict__ out,
    float* __restrict__ esum) {
  const int bid = blockIdx.x;
  const int tid = threadIdx.x;

  if (bid >= NG) {               // ---- fill role: pure HBM write ----
    const int fb = bid - NG;
    const long long total4 = (long long)((OUTN - 1) / 4);   // 33,554,432
    const long long per = (total4 + NF - 1) / NF;
    long long end = (long long)(fb + 1) * per;
    if (end > total4) end = total4;
    const float4 z = make_float4(0.f, 0.f, 0.f, 0.f);
    float4* o4 = (float4*)out;
    for (long long i = (long long)fb * per + tid; i < end; i += 256) o4[i] = z;
    if (fb == 0) {
      if (tid == 0) out[OUTN - 1] = 0.f;        // tail element
      if (tid < NEXP) esum[tid] = 0.f;
    }
    return;
  }

  // ---- GEMM role ----
  // LDS: [buf(2)][plane(2)][e(64)][swizzled 16B slot(8)] = 32 KB
  __shared__ __align__(16) char Bs[4 * 64 * 128];
  const int t0 = bid * 64;

  // staging ids: thread -> (expert row, 16-float quarter of the K64 chunk)
  const int se = tid >> 2;
  const int sq = tid & 3;
  const float* wgp = wg + (size_t)se * MDIM + sq * 16;
  const int s0  = sq * 2;
  const int wo0 = (se << 7) + (((s0)     ^ (se & 7)) << 4);
  const int wo1 = (se << 7) + (((s0 + 1) ^ (se & 7)) << 4);

  // compute ids
  const int wid  = tid >> 6;
  const int lane = tid & 63;
  const int mrow = lane & 15;          // token row in wave tile / expert col
  const int kg   = lane >> 4;          // k-subgroup (8 elems)
  const float* xp = x + (size_t)(t0 + wid * 16 + mrow) * MDIM + kg * 8;

  f32x4 acc[4] = {{0.f,0.f,0.f,0.f},{0.f,0.f,0.f,0.f},
                  {0.f,0.f,0.f,0.f},{0.f,0.f,0.f,0.f}};

  // prologue: stage step 0 into buf 0
  {
    const float4 w0 = *(const float4*)wgp,       w1 = *(const float4*)(wgp + 4);
    const float4 w2 = *(const float4*)(wgp + 8), w3 = *(const float4*)(wgp + 12);
    const float f0[8] = {w0.x,w0.y,w0.z,w0.w,w1.x,w1.y,w1.z,w1.w};
    const float f1[8] = {w2.x,w2.y,w2.z,w2.w,w3.x,w3.y,w3.z,w3.w};
    bf16x8 h, l;
    split8(f0, h, l);
    *(bf16x8*)(Bs + wo0) = h;  *(bf16x8*)(Bs + 8192 + wo0) = l;
    split8(f1, h, l);
    *(bf16x8*)(Bs + wo1) = h;  *(bf16x8*)(Bs + 8192 + wo1) = l;
  }
  __syncthreads();

  for (int kb = 0; kb < NSTEP; ++kb) {
    const int cur = kb & 1;
    const bool pf = (kb + 1) < NSTEP;
    float4 w0, w1, w2, w3;
    if (pf) {                    // issue next B-chunk loads early (L2-resident)
      const float* p = wgp + (kb + 1) * BK;
      w0 = *(const float4*)p;       w1 = *(const float4*)(p + 4);
      w2 = *(const float4*)(p + 8); w3 = *(const float4*)(p + 12);
    }
    // A: 4 coalesced float4 loads + in-register split
    const float* ap = xp + kb * BK;
    const float4 a0 = *(const float4*)ap,        a1 = *(const float4*)(ap + 4);
    const float4 a2 = *(const float4*)(ap + 32), a3 = *(const float4*)(ap + 36);
    bf16x8 ah[2], al[2];
    { const float fa[8] = {a0.x,a0.y,a0.z,a0.w,a1.x,a1.y,a1.z,a1.w};
      split8(fa, ah[0], al[0]); }
    { const float fa[8] = {a2.x,a2.y,a2.z,a2.w,a3.x,a3.y,a3.z,a3.w};
      split8(fa, ah[1], al[1]); }

    const char* bbase = Bs + cur * 16384;
#pragma unroll
    for (int et = 0; et < 4; ++et) {
      const int e   = et * 16 + mrow;
      const int ero = e << 7;
#pragma unroll
      for (int ks = 0; ks < 2; ++ks) {
        const int sw = (((ks * 4 + kg) ^ (e & 7)) << 4);
        const bf16x8 bh = *(const bf16x8*)(bbase + ero + sw);
        const bf16x8 bl = *(const bf16x8*)(bbase + 8192 + ero + sw);
        acc[et] = __builtin_amdgcn_mfma_f32_16x16x32_bf16(ah[ks], bh, acc[et], 0, 0, 0);
        acc[et] = __builtin_amdgcn_mfma_f32_16x16x32_bf16(ah[ks], bl, acc[et], 0, 0, 0);
        acc[et] = __builtin_amdgcn_mfma_f32_16x16x32_bf16(al[ks], bh, acc[et], 0, 0, 0);
      }
    }
    __syncthreads();             // all reads of buf[cur^1] from prev iter done
    if (pf) {
      char* sb = Bs + (cur ^ 1) * 16384;
      const float f0[8] = {w0.x,w0.y,w0.z,w0.w,w1.x,w1.y,w1.z,w1.w};
      const float f1[8] = {w2.x,w2.y,w2.z,w2.w,w3.x,w3.y,w3.z,w3.w};
      bf16x8 h, l;
      split8(f0, h, l);
      *(bf16x8*)(sb + wo0) = h;  *(bf16x8*)(sb + 8192 + wo0) = l;
      split8(f1, h, l);
      *(bf16x8*)(sb + wo1) = h;  *(bf16x8*)(sb + 8192 + wo1) = l;
    }
    __syncthreads();             // staged buf visible before next iter reads
  }

  // C/D layout: col = lane&15 (expert), row = (lane>>4)*4 + reg (token)
#pragma unroll
  for (int et = 0; et < 4; ++et)
#pragma unroll
    for (int r = 0; r < 4; ++r)
      logits[(size_t)(t0 + wid * 16 + kg * 4 + r) * NEXP + et * 16 + mrow] =
          acc[et][r];
}

// ---------------------------------------------------------------------------
// Softmax + argmax (tie -> min index). 16 tokens per block (4 waves x 4).
// ---------------------------------------------------------------------------
__global__ __launch_bounds__(256) void softmax_stats(
    const float* __restrict__ logits, int* __restrict__ idx,
    float* __restrict__ gval, float* __restrict__ esum) {
  const int tid  = threadIdx.x;
  const int wid  = tid >> 6;
  const int lane = tid & 63;

  float gl = 0.f;
#pragma unroll
  for (int j = 0; j < 4; ++j) {
    const int t = blockIdx.x * 16 + wid * 4 + j;
    const float v = logits[(size_t)t * NEXP + lane];
    float m = v; int mi = lane;
#pragma unroll
    for (int d = 32; d >= 1; d >>= 1) {
      const float om = __shfl_xor(m, d);
      const int   oi = __shfl_xor(mi, d);
      if (om > m || (om == m && oi < mi)) { m = om; mi = oi; }
    }
    const float e = expf(v - m);
    float denom = e;
#pragma unroll
    for (int d = 32; d >= 1; d >>= 1) denom += __shfl_xor(denom, d);
    gl += e / denom;
    if (lane == 0) { idx[t] = mi; gval[t] = 1.0f / denom; }
  }

  __shared__ float sg[4][64];
  sg[wid][lane] = gl;
  __syncthreads();
  if (tid < 64)
    atomicAdd(&esum[tid], sg[0][tid] + sg[1][tid] + sg[2][tid] + sg[3][tid]);
}

// ---------------------------------------------------------------------------
// Per-expert scan + scatter + l_aux. One wave per expert, idx staged in LDS.
// ---------------------------------------------------------------------------
__global__ __launch_bounds__(256) void scan_scatter(
    const int* __restrict__ idx, const float* __restrict__ gval,
    const float* __restrict__ esum, float* __restrict__ out) {
  __shared__ int sidx[T_TOK];           // 32 KB
  const int tid = threadIdx.x;
  for (int i = tid; i < T_TOK / 4; i += 256)
    ((int4*)sidx)[i] = ((const int4*)idx)[i];
  __syncthreads();

  const int e    = blockIdx.x * 4 + (tid >> 6);
  const int lane = tid & 63;
  int carry = 0;
#pragma unroll 4
  for (int base = 0; base < T_TOK; base += 64) {
    const int t = base + lane;
    const bool flag = (sidx[t] == e);
    const unsigned long long mask = __ballot(flag);
    if (flag) {
      const int p = carry + __popcll(mask & ((1ull << lane) - 1ull));
      if (p < CAP) {
        const size_t off = ((size_t)t * NEXP + e) * CAP + p;
        out[1 + off]       = gval[t];
        out[1 + TEC + off] = 1.0f;
      }
    }
    carry += __popcll(mask);
  }
  if (lane == 0)                        // ce uses pre-drop count = carry
    atomicAdd(out, esum[e] * (float)carry *
                   ((float)NEXP / ((float)T_TOK * (float)T_TOK)));
}

extern "C" void kernel_launch(void* const* d_in, const int* in_sizes, int n_in,
                              void* d_out, int out_size, void* d_ws, size_t ws_size,
                              hipStream_t stream) {
  const float* x  = (const float*)d_in[0];
  const float* wg = (const float*)d_in[1];
  float* out = (float*)d_out;

  float* logits = (float*)d_ws;                             // T*E f32 (2 MB)
  int*   idx    = (int*)(logits + (size_t)T_TOK * NEXP);
  float* gval   = (float*)(idx + T_TOK);
  float* esum   = (float*)(gval + T_TOK);

  gemm_fill<<<NG + NF, 256, 0, stream>>>(x, wg, logits, out, esum);
  softmax_stats<<<T_TOK / 16, 256, 0, stream>>>(logits, idx, gval, esum);
  scan_scatter<<<NEXP / 4, 256, 0, stream>>>(idx, gval, esum, out);
}

// Round 5
// 216.086 us; speedup vs baseline: 1.2237x; 1.1031x over previous
//
#include <hip/hip_runtime.h>
#include <hip/hip_bf16.h>
#include <cstdint>
#include <cstddef>

#define T_TOK 8192
#define MDIM  4096
#define NEXP  64
#define CAP   128
#define TEC   ((size_t)T_TOK * NEXP * CAP)        // 67,108,864
#define OUTN  ((size_t)(1 + 2 * TEC))             // 134,217,729 floats
#define BM    32
#define NBLK  (T_TOK / BM)                        // 256 blocks
#define BK    64
#define NSTEP (MDIM / BK)                         // 64

typedef __attribute__((ext_vector_type(8))) short bf16x8;   // 8 bf16 = 4 VGPR
typedef __attribute__((ext_vector_type(4))) float f32x4;    // MFMA acc

// split f32 -> hi bf16 + lo bf16 (residual), |err| ~ 2^-18 relative
__device__ __forceinline__ void split8(const float* f, bf16x8& h, bf16x8& l) {
#pragma unroll
  for (int j = 0; j < 8; ++j) {
    const __hip_bfloat16 hb = __float2bfloat16(f[j]);
    const float r = f[j] - __bfloat162float(hb);
    h[j] = __builtin_bit_cast(short, hb);
    l[j] = __builtin_bit_cast(short, __float2bfloat16(r));
  }
}

// stage 32 f32 of wg (two 16B-slot pairs) into hi/lo planes at sb
__device__ __forceinline__ void stageB(char* sb, const float4& w0,
                                       const float4& w1, const float4& w2,
                                       const float4& w3, int wo0, int wo1) {
  const float f0[8] = {w0.x, w0.y, w0.z, w0.w, w1.x, w1.y, w1.z, w1.w};
  const float f1[8] = {w2.x, w2.y, w2.z, w2.w, w3.x, w3.y, w3.z, w3.w};
  bf16x8 h, l;
  split8(f0, h, l);
  *(bf16x8*)(sb + wo0) = h;  *(bf16x8*)(sb + 8192 + wo0) = l;
  split8(f1, h, l);
  *(bf16x8*)(sb + wo1) = h;  *(bf16x8*)(sb + 8192 + wo1) = l;
}

// ---------------------------------------------------------------------------
// Logits GEMM: 32 tokens x 64 experts x K=4096 per block, 4 waves
// (wave = (token-half tr, expert-half eh): 16 tokens x 32 experts).
// B LDS-staged (split-bf16, XOR-swizzled, double-buffered);
// A global->reg->split, prefetched one K-step ahead.
// ---------------------------------------------------------------------------
__global__ __launch_bounds__(256) void gemm_logits(
    const float* __restrict__ x, const float* __restrict__ wg,
    float* __restrict__ logits) {
  // LDS: [buf(2)][plane(2)][e(64)][swizzled 16B slot(8)] = 32 KB
  __shared__ __align__(16) char Bs[4 * 64 * 128];
  const int tid = threadIdx.x;
  const int t0  = blockIdx.x * BM;

  // staging ids: thread -> (expert row se, 16-float quarter sq of K64 chunk)
  const int se = tid >> 2;
  const int sq = tid & 3;
  const float* wgp = wg + (size_t)se * MDIM + sq * 16;
  const int wo0 = (se << 7) + (((sq * 2)     ^ (se & 7)) << 4);
  const int wo1 = (se << 7) + (((sq * 2 + 1) ^ (se & 7)) << 4);

  // compute ids
  const int wid  = tid >> 6;
  const int lane = tid & 63;
  const int tr   = wid & 1;            // token 16-row half
  const int eh   = wid >> 1;           // expert 32-col half
  const int mrow = lane & 15;
  const int kg   = lane >> 4;
  const float* xp = x + (size_t)(t0 + tr * 16 + mrow) * MDIM + kg * 8;

  f32x4 acc[2] = {{0.f,0.f,0.f,0.f},{0.f,0.f,0.f,0.f}};

  // prologue: stage B step 0 into buf0; load A(0); load B(1) to regs
  {
    const float4 w0 = *(const float4*)wgp,       w1 = *(const float4*)(wgp + 4);
    const float4 w2 = *(const float4*)(wgp + 8), w3 = *(const float4*)(wgp + 12);
    stageB(Bs, w0, w1, w2, w3, wo0, wo1);
  }
  float4 ca0 = *(const float4*)xp,        ca1 = *(const float4*)(xp + 4);
  float4 ca2 = *(const float4*)(xp + 32), ca3 = *(const float4*)(xp + 36);
  float4 nw0, nw1, nw2, nw3;
  {
    const float* p = wgp + BK;
    nw0 = *(const float4*)p;       nw1 = *(const float4*)(p + 4);
    nw2 = *(const float4*)(p + 8); nw3 = *(const float4*)(p + 12);
  }
  __syncthreads();

#pragma unroll 2
  for (int kb = 0; kb < NSTEP; ++kb) {
    const int cur = kb & 1;
    const bool pf = (kb + 1) < NSTEP;
    // prefetch next A into regs (independent; hides HBM latency under MFMA)
    float4 na0, na1, na2, na3;
    if (pf) {
      const float* ap = xp + (kb + 1) * BK;
      na0 = *(const float4*)ap;        na1 = *(const float4*)(ap + 4);
      na2 = *(const float4*)(ap + 32); na3 = *(const float4*)(ap + 36);
    }
    // split current A
    bf16x8 ah[2], al[2];
    { const float fa[8] = {ca0.x,ca0.y,ca0.z,ca0.w,ca1.x,ca1.y,ca1.z,ca1.w};
      split8(fa, ah[0], al[0]); }
    { const float fa[8] = {ca2.x,ca2.y,ca2.z,ca2.w,ca3.x,ca3.y,ca3.z,ca3.w};
      split8(fa, ah[1], al[1]); }

    const char* bbase = Bs + cur * 16384;
#pragma unroll
    for (int et = 0; et < 2; ++et) {
      const int e   = eh * 32 + et * 16 + mrow;
      const int ero = e << 7;
#pragma unroll
      for (int ks = 0; ks < 2; ++ks) {
        const int sw = (((ks * 4 + kg) ^ (e & 7)) << 4);
        const bf16x8 bh = *(const bf16x8*)(bbase + ero + sw);
        const bf16x8 bl = *(const bf16x8*)(bbase + 8192 + ero + sw);
        acc[et] = __builtin_amdgcn_mfma_f32_16x16x32_bf16(ah[ks], bh, acc[et], 0, 0, 0);
        acc[et] = __builtin_amdgcn_mfma_f32_16x16x32_bf16(ah[ks], bl, acc[et], 0, 0, 0);
        acc[et] = __builtin_amdgcn_mfma_f32_16x16x32_bf16(al[ks], bh, acc[et], 0, 0, 0);
      }
    }
    __syncthreads();             // prev buf reads done before overwrite
    if (pf) {
      stageB(Bs + (cur ^ 1) * 16384, nw0, nw1, nw2, nw3, wo0, wo1);
      if (kb + 2 < NSTEP) {      // reload B regs for step kb+2 (L2-hot)
        const float* p = wgp + (kb + 2) * BK;
        nw0 = *(const float4*)p;       nw1 = *(const float4*)(p + 4);
        nw2 = *(const float4*)(p + 8); nw3 = *(const float4*)(p + 12);
      }
      ca0 = na0; ca1 = na1; ca2 = na2; ca3 = na3;
    }
    __syncthreads();             // staged buf visible before next reads
  }

  // C/D layout: col = lane&15 (expert within tile), row = (lane>>4)*4 + reg
#pragma unroll
  for (int et = 0; et < 2; ++et)
#pragma unroll
    for (int r = 0; r < 4; ++r)
      logits[(size_t)(t0 + tr * 16 + kg * 4 + r) * NEXP +
             eh * 32 + et * 16 + mrow] = acc[et][r];
}

// ---------------------------------------------------------------------------
// Softmax + argmax (tie -> min index). 16 tokens per block (4 waves x 4).
// ---------------------------------------------------------------------------
__global__ __launch_bounds__(256) void softmax_stats(
    const float* __restrict__ logits, int* __restrict__ idx,
    float* __restrict__ gval, float* __restrict__ esum) {
  const int tid  = threadIdx.x;
  const int wid  = tid >> 6;
  const int lane = tid & 63;

  float gl = 0.f;
#pragma unroll
  for (int j = 0; j < 4; ++j) {
    const int t = blockIdx.x * 16 + wid * 4 + j;
    const float v = logits[(size_t)t * NEXP + lane];
    float m = v; int mi = lane;
#pragma unroll
    for (int d = 32; d >= 1; d >>= 1) {
      const float om = __shfl_xor(m, d);
      const int   oi = __shfl_xor(mi, d);
      if (om > m || (om == m && oi < mi)) { m = om; mi = oi; }
    }
    const float e = expf(v - m);
    float denom = e;
#pragma unroll
    for (int d = 32; d >= 1; d >>= 1) denom += __shfl_xor(denom, d);
    gl += e / denom;
    if (lane == 0) { idx[t] = mi; gval[t] = 1.0f / denom; }
  }

  __shared__ float sg[4][64];
  sg[wid][lane] = gl;
  __syncthreads();
  if (tid < 64)
    atomicAdd(&esum[tid], sg[0][tid] + sg[1][tid] + sg[2][tid] + sg[3][tid]);
}

// ---------------------------------------------------------------------------
// Per-expert scan + scatter + l_aux. One wave per expert, idx staged in LDS.
// ---------------------------------------------------------------------------
__global__ __launch_bounds__(256) void scan_scatter(
    const int* __restrict__ idx, const float* __restrict__ gval,
    const float* __restrict__ esum, float* __restrict__ out) {
  __shared__ int sidx[T_TOK];           // 32 KB
  const int tid = threadIdx.x;
  for (int i = tid; i < T_TOK / 4; i += 256)
    ((int4*)sidx)[i] = ((const int4*)idx)[i];
  __syncthreads();

  const int e    = blockIdx.x * 4 + (tid >> 6);
  const int lane = tid & 63;
  int carry = 0;
#pragma unroll 4
  for (int base = 0; base < T_TOK; base += 64) {
    const int t = base + lane;
    const bool flag = (sidx[t] == e);
    const unsigned long long mask = __ballot(flag);
    if (flag) {
      const int p = carry + __popcll(mask & ((1ull << lane) - 1ull));
      if (p < CAP) {
        const size_t off = ((size_t)t * NEXP + e) * CAP + p;
        out[1 + off]       = gval[t];
        out[1 + TEC + off] = 1.0f;
      }
    }
    carry += __popcll(mask);
  }
  if (lane == 0)                        // ce uses pre-drop count = carry
    atomicAdd(out, esum[e] * (float)carry *
                   ((float)NEXP / ((float)T_TOK * (float)T_TOK)));
}

extern "C" void kernel_launch(void* const* d_in, const int* in_sizes, int n_in,
                              void* d_out, int out_size, void* d_ws, size_t ws_size,
                              hipStream_t stream) {
  const float* x  = (const float*)d_in[0];
  const float* wg = (const float*)d_in[1];
  float* out = (float*)d_out;

  float* logits = (float*)d_ws;                             // T*E f32 (2 MB)
  int*   idx    = (int*)(logits + (size_t)T_TOK * NEXP);
  float* gval   = (float*)(idx + T_TOK);
  float* esum   = (float*)(gval + T_TOK);

  hipMemsetAsync(out, 0, OUTN * sizeof(float), stream);     // rocclr fill ~79us
  hipMemsetAsync(esum, 0, NEXP * sizeof(float), stream);

  gemm_logits<<<NBLK, 256, 0, stream>>>(x, wg, logits);
  softmax_stats<<<T_TOK / 16, 256, 0, stream>>>(logits, idx, gval, esum);
  scan_scatter<<<NEXP / 4, 256, 0, stream>>>(idx, gval, esum, out);
}